// Round 1
// baseline (1107.429 us; speedup 1.0000x reference)
//
#include <hip/hip_runtime.h>
#include <hip/hip_bf16.h>

#define N_ATOMS 100000
#define N_RES   12500
#define N_EDGES 800000
#define D_IN    37
#define D       115
#define DP      128            // padded feature dim (bf16 row = 256 B)
#define MPAD    100096         // atoms padded to multiple of 128
#define N_LAYERS 4

typedef __bf16 bf16x8 __attribute__((ext_vector_type(8)));
typedef float  f32x4  __attribute__((ext_vector_type(4)));
typedef unsigned int u32x4 __attribute__((ext_vector_type(4)));

__device__ __forceinline__ unsigned short f2bf(float f) {
  unsigned u = __builtin_bit_cast(unsigned, f);
  u += 0x7fffu + ((u >> 16) & 1u);            // RNE
  return (unsigned short)(u >> 16);
}
__device__ __forceinline__ float bf2f(unsigned short h) {
  unsigned u = ((unsigned)h) << 16;
  return __builtin_bit_cast(float, u);
}
__device__ __forceinline__ bf16x8 ld_frag(const unsigned short* p) {
  u32x4 u = *reinterpret_cast<const u32x4*>(p);
  return __builtin_bit_cast(bf16x8, u);
}

// ---- CSR build -------------------------------------------------------------
__global__ void k_hist_edges(const int* __restrict__ eidx, int* __restrict__ hist) {
  int e = blockIdx.x * blockDim.x + threadIdx.x;
  if (e < N_EDGES) atomicAdd(&hist[eidx[N_EDGES + e]], 1);
}
__global__ void k_hist_res(const int* __restrict__ r2a, int* __restrict__ rhist) {
  int a = blockIdx.x * blockDim.x + threadIdx.x;
  if (a < N_ATOMS) atomicAdd(&rhist[r2a[a]], 1);
}
// single-block exclusive scan (n <= 1024*chunk); optionally writes cursor copy
// and inv_deg = 1/max(cnt,1)
__global__ __launch_bounds__(1024) void k_scan(
    const int* __restrict__ cnt, int n,
    int* __restrict__ offs, int* __restrict__ cursor, float* __restrict__ invdeg)
{
  __shared__ int part[1024];
  const int t = threadIdx.x;
  const int chunk = (n + 1023) >> 10;
  const int b = t * chunk;
  const int e = min(n, b + chunk);
  int s = 0;
  for (int i = b; i < e; ++i) s += cnt[i];
  part[t] = s;
  __syncthreads();
  for (int d = 1; d < 1024; d <<= 1) {
    int v = (t >= d) ? part[t - d] : 0;
    __syncthreads();
    part[t] += v;
    __syncthreads();
  }
  int run = (t == 0) ? 0 : part[t - 1];
  for (int i = b; i < e; ++i) {
    offs[i] = run;
    if (cursor) cursor[i] = run;
    if (invdeg) invdeg[i] = 1.0f / (float)max(cnt[i], 1);
    run += cnt[i];
  }
  if (t == 1023) offs[n] = part[1023];
}
__global__ void k_fill(const int* __restrict__ eidx, int* __restrict__ cursor,
                       int* __restrict__ srcs) {
  int e = blockIdx.x * blockDim.x + threadIdx.x;
  if (e < N_EDGES) {
    int s = eidx[e], d = eidx[N_EDGES + e];
    int pos = atomicAdd(&cursor[d], 1);
    srcs[pos] = s;
  }
}

// ---- weight pad/convert: W[115][115] f32 -> [128][128] bf16 (c-major) ------
__global__ void k_convw(const float* __restrict__ Wl, const float* __restrict__ Wr,
                        unsigned short* __restrict__ wpad)
{
  const int k = threadIdx.x;   // 0..127
  const int c = blockIdx.x;    // 0..127
  const int m = blockIdx.y;    // 0..7  (0-3 = Wl layers, 4-7 = Wr layers)
  const float* src = (m < 4) ? (Wl + m * D * D) : (Wr + (m - 4) * D * D);
  unsigned short v = 0;
  if (c < D && k < D) v = f2bf(src[c * D + k]);
  wpad[(m * 128 + c) * 128 + k] = v;
}

// ---- input projection: x0 = A @ lnW^T + lnb, write bf16 [MPAD][128] --------
__global__ __launch_bounds__(128) void k_proj(
    const float* __restrict__ A, const float* __restrict__ Wf,
    const float* __restrict__ bf, unsigned short* __restrict__ xout)
{
  __shared__ float sW[D * D_IN];
  __shared__ float sA[32][D_IN];
  const int t = threadIdx.x;
  for (int i = t; i < D * D_IN; i += 128) sW[i] = Wf[i];
  const int r0 = blockIdx.x * 32;
  for (int i = t; i < 32 * D_IN; i += 128) {
    int r = i / D_IN, k = i - r * D_IN;
    int gr = r0 + r;
    sA[r][k] = (gr < N_ATOMS) ? A[gr * D_IN + k] : 0.f;
  }
  __syncthreads();
  const int c = t;
  const float bias = (c < D) ? bf[c] : 0.f;
  for (int r = 0; r < 32; ++r) {
    const int gr = r0 + r;
    if (gr >= N_ATOMS) break;
    if (c < D) {
      float acc = bias;
      #pragma unroll
      for (int k = 0; k < D_IN; ++k) acc += sA[r][k] * sW[c * D_IN + k];
      xout[gr * DP + c] = f2bf(acc);
    } else {
      xout[gr * DP + c] = 0;   // keep K-pad zero
    }
  }
}

// ---- CSR mean aggregation: one wave per node, 64 lanes x 2 bf16 ------------
__global__ __launch_bounds__(256) void k_agg(
    const unsigned int* __restrict__ xin, const int* __restrict__ row_start,
    const int* __restrict__ srcs, const float* __restrict__ invdeg,
    unsigned int* __restrict__ aggout)
{
  const int w = (int)((blockIdx.x * 256 + threadIdx.x) >> 6);
  const int lane = threadIdx.x & 63;
  if (w >= N_ATOMS) return;
  const int beg = row_start[w], end = row_start[w + 1];
  float a0 = 0.f, a1 = 0.f;
  for (int j = beg; j < end; ++j) {
    const int s = srcs[j];
    unsigned int v = xin[s * 64 + lane];
    a0 += bf2f((unsigned short)(v & 0xffffu));
    a1 += bf2f((unsigned short)(v >> 16));
  }
  const float sc = invdeg[w];
  unsigned int o = (unsigned int)f2bf(a0 * sc) | ((unsigned int)f2bf(a1 * sc) << 16);
  aggout[w * 64 + lane] = o;
}

// ---- fused layer GEMM: xout = agg @ Wl^T + x @ Wr^T + bl  (K=256 concat) ---
__global__ __launch_bounds__(256) void k_gemm(
    const unsigned short* __restrict__ agg,
    const unsigned short* __restrict__ xin,
    const unsigned short* __restrict__ wl,   // [128][128] bf16, c-major
    const unsigned short* __restrict__ wr,
    const float* __restrict__ bias,          // 115 floats
    unsigned short* __restrict__ xout)
{
  const int lane = threadIdx.x & 63;
  const int wid  = threadIdx.x >> 6;
  const int row0 = blockIdx.x * 128 + wid * 32;   // wave owns 32 rows
  const int lrow = lane & 15;
  const int koff = (lane >> 4) * 8;

  f32x4 acc[2][8];
  #pragma unroll
  for (int i = 0; i < 2; ++i)
    #pragma unroll
    for (int j = 0; j < 8; ++j)
      acc[i][j] = (f32x4){0.f, 0.f, 0.f, 0.f};

  #pragma unroll
  for (int s = 0; s < 2; ++s) {
    const unsigned short* X = s ? xin : agg;
    const unsigned short* W = s ? wr : wl;
    #pragma unroll
    for (int ks = 0; ks < 4; ++ks) {
      const int k0 = ks * 32 + koff;
      bf16x8 a0 = ld_frag(&X[(size_t)(row0 + lrow) * DP + k0]);
      bf16x8 a1 = ld_frag(&X[(size_t)(row0 + 16 + lrow) * DP + k0]);
      #pragma unroll
      for (int ct = 0; ct < 8; ++ct) {
        bf16x8 b = ld_frag(&W[(ct * 16 + lrow) * DP + k0]);
        acc[0][ct] = __builtin_amdgcn_mfma_f32_16x16x32_bf16(a0, b, acc[0][ct], 0, 0, 0);
        acc[1][ct] = __builtin_amdgcn_mfma_f32_16x16x32_bf16(a1, b, acc[1][ct], 0, 0, 0);
      }
    }
  }

  const int ocol = lane & 15;
  const int orow = (lane >> 4) * 4;   // C/D: col=lane&15, row=(lane>>4)*4+reg
  #pragma unroll
  for (int ct = 0; ct < 8; ++ct) {
    const int col = ct * 16 + ocol;
    const float bv = (col < D) ? bias[col] : 0.f;
    #pragma unroll
    for (int rt = 0; rt < 2; ++rt) {
      #pragma unroll
      for (int j = 0; j < 4; ++j) {
        const int grow = row0 + rt * 16 + orow + j;
        if (grow < N_ATOMS)
          xout[(size_t)grow * DP + col] = f2bf(acc[rt][ct][j] + bv);
      }
    }
  }
}

// ---- residue pooling: sorted segment-sum, one wave per residue -------------
__global__ __launch_bounds__(256) void k_pool(
    const unsigned int* __restrict__ x, const int* __restrict__ res_start,
    float* __restrict__ out)
{
  const int r = (int)((blockIdx.x * 256 + threadIdx.x) >> 6);
  const int lane = threadIdx.x & 63;
  if (r >= N_RES) return;
  const int beg = res_start[r], end = res_start[r + 1];
  float a0 = 0.f, a1 = 0.f;
  for (int a = beg; a < end; ++a) {
    unsigned int v = x[a * 64 + lane];
    a0 += bf2f((unsigned short)(v & 0xffffu));
    a1 += bf2f((unsigned short)(v >> 16));
  }
  const int c0 = lane * 2;
  if (c0 < D)     out[(size_t)r * D + c0]     = a0;
  if (c0 + 1 < D) out[(size_t)r * D + c0 + 1] = a1;
}

extern "C" void kernel_launch(void* const* d_in, const int* in_sizes, int n_in,
                              void* d_out, int out_size, void* d_ws, size_t ws_size,
                              hipStream_t stream)
{
  (void)in_sizes; (void)n_in; (void)out_size; (void)ws_size;
  const float* atom_emb = (const float*)d_in[1];
  const int*   eidx     = (const int*)d_in[2];
  const int*   r2a      = (const int*)d_in[3];
  const float* lnW      = (const float*)d_in[4];
  const float* lnb      = (const float*)d_in[5];
  const float* Wl       = (const float*)d_in[6];
  const float* Wr       = (const float*)d_in[7];
  const float* bl       = (const float*)d_in[8];
  float* out = (float*)d_out;

  // workspace carve-out (~82 MB total)
  char* p = (char*)d_ws;
  auto alloc = [&](size_t b) { char* r = p; p += (b + 255) & ~(size_t)255; return r; };
  unsigned short* xb0  = (unsigned short*)alloc((size_t)MPAD * DP * 2);
  unsigned short* xb1  = (unsigned short*)alloc((size_t)MPAD * DP * 2);
  unsigned short* xb2  = (unsigned short*)alloc((size_t)MPAD * DP * 2);
  unsigned short* wpad = (unsigned short*)alloc((size_t)8 * 128 * 128 * 2);
  int*   hist      = (int*)alloc((size_t)N_ATOMS * 4);
  int*   row_start = (int*)alloc((size_t)(N_ATOMS + 1) * 4);
  int*   cursor    = (int*)alloc((size_t)N_ATOMS * 4);
  float* invdeg    = (float*)alloc((size_t)N_ATOMS * 4);
  int*   srcs      = (int*)alloc((size_t)N_EDGES * 4);
  int*   rhist     = (int*)alloc((size_t)N_RES * 4);
  int*   res_start = (int*)alloc((size_t)(N_RES + 1) * 4);

  hipMemsetAsync(hist, 0, (size_t)N_ATOMS * 4, stream);
  hipMemsetAsync(rhist, 0, (size_t)N_RES * 4, stream);

  k_convw<<<dim3(128, 8), 128, 0, stream>>>(Wl, Wr, wpad);
  k_hist_edges<<<(N_EDGES + 255) / 256, 256, 0, stream>>>(eidx, hist);
  k_hist_res<<<(N_ATOMS + 255) / 256, 256, 0, stream>>>(r2a, rhist);
  k_scan<<<1, 1024, 0, stream>>>(hist, N_ATOMS, row_start, cursor, invdeg);
  k_scan<<<1, 1024, 0, stream>>>(rhist, N_RES, res_start, (int*)nullptr, (float*)nullptr);
  k_fill<<<(N_EDGES + 255) / 256, 256, 0, stream>>>(eidx, cursor, srcs);
  k_proj<<<(N_ATOMS + 31) / 32, 128, 0, stream>>>(atom_emb, lnW, lnb, xb0);

  unsigned short* bufs[3] = {xb0, xb1, xb2};
  int cur = 0;
  for (int l = 0; l < N_LAYERS; ++l) {
    unsigned short* xin  = bufs[cur];
    unsigned short* aggb = bufs[(cur + 1) % 3];
    unsigned short* xo   = bufs[(cur + 2) % 3];
    k_agg<<<(N_ATOMS * 64) / 256, 256, 0, stream>>>(
        (const unsigned int*)xin, row_start, srcs, invdeg, (unsigned int*)aggb);
    k_gemm<<<MPAD / 128, 256, 0, stream>>>(
        aggb, xin, wpad + (size_t)l * 16384, wpad + (size_t)(4 + l) * 16384,
        bl + (size_t)l * D, xo);
    cur = (cur + 2) % 3;
  }
  k_pool<<<(N_RES * 64) / 256, 256, 0, stream>>>(
      (const unsigned int*)bufs[cur], res_start, out);
}

// Round 2
// 833.042 us; speedup vs baseline: 1.3294x; 1.3294x over previous
//
#include <hip/hip_runtime.h>
#include <hip/hip_bf16.h>

#define N_ATOMS 100000
#define N_RES   12500
#define N_EDGES 800000
#define D_IN    37
#define D       115
#define DP      128            // padded feature dim (bf16 row = 256 B)
#define MPAD    100096         // atoms padded to multiple of 128
#define N_LAYERS 4
#define SCE     1024           // elements per scan block (256 thr x 4)
#define NSCB    ((N_ATOMS + SCE - 1) / SCE)   // 98 scan blocks

typedef __bf16 bf16x8 __attribute__((ext_vector_type(8)));
typedef float  f32x4  __attribute__((ext_vector_type(4)));
typedef unsigned int u32x4 __attribute__((ext_vector_type(4)));

__device__ __forceinline__ unsigned short f2bf(float f) {
  unsigned u = __builtin_bit_cast(unsigned, f);
  u += 0x7fffu + ((u >> 16) & 1u);            // RNE
  return (unsigned short)(u >> 16);
}
__device__ __forceinline__ float bf2f(unsigned short h) {
  unsigned u = ((unsigned)h) << 16;
  return __builtin_bit_cast(float, u);
}
__device__ __forceinline__ bf16x8 ld_frag(const unsigned short* p) {
  u32x4 u = *reinterpret_cast<const u32x4*>(p);
  return __builtin_bit_cast(bf16x8, u);
}

// ---- CSR build -------------------------------------------------------------
__global__ void k_hist_edges(const int* __restrict__ eidx, int* __restrict__ hist) {
  int e = blockIdx.x * blockDim.x + threadIdx.x;
  if (e < N_EDGES) atomicAdd(&hist[eidx[N_EDGES + e]], 1);
}

// 3-phase device-wide exclusive scan over N_ATOMS counts
__global__ __launch_bounds__(256) void k_scan_part(
    const int* __restrict__ cnt, int* __restrict__ bsum)
{
  __shared__ int sh[256];
  const int t = threadIdx.x, b = blockIdx.x;
  const int base = b * SCE + t * 4;
  int s = 0;
  #pragma unroll
  for (int i = 0; i < 4; ++i) { int id = base + i; if (id < N_ATOMS) s += cnt[id]; }
  sh[t] = s; __syncthreads();
  for (int d = 128; d > 0; d >>= 1) { if (t < d) sh[t] += sh[t + d]; __syncthreads(); }
  if (t == 0) bsum[b] = sh[0];
}
__global__ __launch_bounds__(256) void k_scan_bsum(
    int* __restrict__ bsum, int* __restrict__ total)
{
  __shared__ int sh[256];
  const int t = threadIdx.x;
  int v = (t < NSCB) ? bsum[t] : 0;
  sh[t] = v; __syncthreads();
  for (int d = 1; d < 256; d <<= 1) {
    int u = (t >= d) ? sh[t - d] : 0;
    __syncthreads();
    sh[t] += u;
    __syncthreads();
  }
  if (t < NSCB) bsum[t] = sh[t] - v;          // exclusive
  if (t == 255) *total = sh[255];             // offs[N_ATOMS]
}
__global__ __launch_bounds__(256) void k_scan_final(
    const int* __restrict__ cnt, const int* __restrict__ bsum,
    int* __restrict__ offs, int* __restrict__ cursor, float* __restrict__ invdeg)
{
  __shared__ int sh[256];
  const int t = threadIdx.x, b = blockIdx.x;
  const int base = b * SCE + t * 4;
  int c[4]; int s = 0;
  #pragma unroll
  for (int i = 0; i < 4; ++i) {
    int id = base + i;
    c[i] = (id < N_ATOMS) ? cnt[id] : 0;
    s += c[i];
  }
  sh[t] = s; __syncthreads();
  for (int d = 1; d < 256; d <<= 1) {
    int u = (t >= d) ? sh[t - d] : 0;
    __syncthreads();
    sh[t] += u;
    __syncthreads();
  }
  int run = bsum[b] + sh[t] - s;              // exclusive prefix for this thread
  #pragma unroll
  for (int i = 0; i < 4; ++i) {
    int id = base + i;
    if (id < N_ATOMS) {
      offs[id] = run;
      cursor[id] = run;
      invdeg[id] = 1.0f / (float)max(c[i], 1);
      run += c[i];
    }
  }
}

// residue CSR via binary search (r2a is sorted): res_start[r] = lower_bound(r)
__global__ __launch_bounds__(256) void k_res_bounds(
    const int* __restrict__ r2a, int* __restrict__ res_start)
{
  int r = blockIdx.x * blockDim.x + threadIdx.x;
  if (r > N_RES) return;
  int lo = 0, hi = N_ATOMS;
  while (lo < hi) {
    int mid = (lo + hi) >> 1;
    if (r2a[mid] < r) lo = mid + 1; else hi = mid;
  }
  res_start[r] = lo;
}

__global__ void k_fill(const int* __restrict__ eidx, int* __restrict__ cursor,
                       int* __restrict__ srcs) {
  int e = blockIdx.x * blockDim.x + threadIdx.x;
  if (e < N_EDGES) {
    int s = eidx[e], d = eidx[N_EDGES + e];
    int pos = atomicAdd(&cursor[d], 1);
    srcs[pos] = s;
  }
}

// ---- weight pad/convert: W[115][115] f32 -> [128][128] bf16 (c-major) ------
__global__ void k_convw(const float* __restrict__ Wl, const float* __restrict__ Wr,
                        unsigned short* __restrict__ wpad)
{
  const int k = threadIdx.x;   // 0..127
  const int c = blockIdx.x;    // 0..127
  const int m = blockIdx.y;    // 0..7  (0-3 = Wl layers, 4-7 = Wr layers)
  const float* src = (m < 4) ? (Wl + m * D * D) : (Wr + (m - 4) * D * D);
  unsigned short v = 0;
  if (c < D && k < D) v = f2bf(src[c * D + k]);
  wpad[(m * 128 + c) * 128 + k] = v;
}

// ---- input projection: x0 = A @ lnW^T + lnb, write bf16 [MPAD][128] --------
__global__ __launch_bounds__(128) void k_proj(
    const float* __restrict__ A, const float* __restrict__ Wf,
    const float* __restrict__ bf, unsigned short* __restrict__ xout)
{
  __shared__ float sW[D * D_IN];
  __shared__ float sA[32][D_IN];
  const int t = threadIdx.x;
  for (int i = t; i < D * D_IN; i += 128) sW[i] = Wf[i];
  const int r0 = blockIdx.x * 32;
  for (int i = t; i < 32 * D_IN; i += 128) {
    int r = i / D_IN, k = i - r * D_IN;
    int gr = r0 + r;
    sA[r][k] = (gr < N_ATOMS) ? A[gr * D_IN + k] : 0.f;
  }
  __syncthreads();
  const int c = t;
  const float bias = (c < D) ? bf[c] : 0.f;
  for (int r = 0; r < 32; ++r) {
    const int gr = r0 + r;
    if (gr >= N_ATOMS) break;
    if (c < D) {
      float acc = bias;
      #pragma unroll
      for (int k = 0; k < D_IN; ++k) acc += sA[r][k] * sW[c * D_IN + k];
      xout[gr * DP + c] = f2bf(acc);
    } else {
      xout[gr * DP + c] = 0;   // keep K-pad zero
    }
  }
}

// ---- CSR mean aggregation: one wave per node, 64 lanes x 2 bf16 ------------
__global__ __launch_bounds__(256) void k_agg(
    const unsigned int* __restrict__ xin, const int* __restrict__ row_start,
    const int* __restrict__ srcs, const float* __restrict__ invdeg,
    unsigned int* __restrict__ aggout)
{
  const int w = (int)((blockIdx.x * 256 + threadIdx.x) >> 6);
  const int lane = threadIdx.x & 63;
  if (w >= N_ATOMS) return;
  const int beg = row_start[w], end = row_start[w + 1];
  float a0 = 0.f, a1 = 0.f;
  for (int j = beg; j < end; ++j) {
    const int s = srcs[j];
    unsigned int v = xin[s * 64 + lane];
    a0 += bf2f((unsigned short)(v & 0xffffu));
    a1 += bf2f((unsigned short)(v >> 16));
  }
  const float sc = invdeg[w];
  unsigned int o = (unsigned int)f2bf(a0 * sc) | ((unsigned int)f2bf(a1 * sc) << 16);
  aggout[w * 64 + lane] = o;
}

// ---- fused layer GEMM: xout = agg @ Wl^T + x @ Wr^T + bl  (K=256 concat) ---
__global__ __launch_bounds__(256) void k_gemm(
    const unsigned short* __restrict__ agg,
    const unsigned short* __restrict__ xin,
    const unsigned short* __restrict__ wl,   // [128][128] bf16, c-major
    const unsigned short* __restrict__ wr,
    const float* __restrict__ bias,          // 115 floats
    unsigned short* __restrict__ xout)
{
  const int lane = threadIdx.x & 63;
  const int wid  = threadIdx.x >> 6;
  const int row0 = blockIdx.x * 128 + wid * 32;   // wave owns 32 rows
  const int lrow = lane & 15;
  const int koff = (lane >> 4) * 8;

  f32x4 acc[2][8];
  #pragma unroll
  for (int i = 0; i < 2; ++i)
    #pragma unroll
    for (int j = 0; j < 8; ++j)
      acc[i][j] = (f32x4){0.f, 0.f, 0.f, 0.f};

  #pragma unroll
  for (int s = 0; s < 2; ++s) {
    const unsigned short* X = s ? xin : agg;
    const unsigned short* W = s ? wr : wl;
    #pragma unroll
    for (int ks = 0; ks < 4; ++ks) {
      const int k0 = ks * 32 + koff;
      bf16x8 a0 = ld_frag(&X[(size_t)(row0 + lrow) * DP + k0]);
      bf16x8 a1 = ld_frag(&X[(size_t)(row0 + 16 + lrow) * DP + k0]);
      #pragma unroll
      for (int ct = 0; ct < 8; ++ct) {
        bf16x8 b = ld_frag(&W[(ct * 16 + lrow) * DP + k0]);
        acc[0][ct] = __builtin_amdgcn_mfma_f32_16x16x32_bf16(a0, b, acc[0][ct], 0, 0, 0);
        acc[1][ct] = __builtin_amdgcn_mfma_f32_16x16x32_bf16(a1, b, acc[1][ct], 0, 0, 0);
      }
    }
  }

  const int ocol = lane & 15;
  const int orow = (lane >> 4) * 4;   // C/D: col=lane&15, row=(lane>>4)*4+reg
  #pragma unroll
  for (int ct = 0; ct < 8; ++ct) {
    const int col = ct * 16 + ocol;
    const float bv = (col < D) ? bias[col] : 0.f;
    #pragma unroll
    for (int rt = 0; rt < 2; ++rt) {
      #pragma unroll
      for (int j = 0; j < 4; ++j) {
        const int grow = row0 + rt * 16 + orow + j;
        if (grow < N_ATOMS)
          xout[(size_t)grow * DP + col] = f2bf(acc[rt][ct][j] + bv);
      }
    }
  }
}

// ---- residue pooling: sorted segment-sum, one wave per residue -------------
__global__ __launch_bounds__(256) void k_pool(
    const unsigned int* __restrict__ x, const int* __restrict__ res_start,
    float* __restrict__ out)
{
  const int r = (int)((blockIdx.x * 256 + threadIdx.x) >> 6);
  const int lane = threadIdx.x & 63;
  if (r >= N_RES) return;
  const int beg = res_start[r], end = res_start[r + 1];
  float a0 = 0.f, a1 = 0.f;
  for (int a = beg; a < end; ++a) {
    unsigned int v = x[a * 64 + lane];
    a0 += bf2f((unsigned short)(v & 0xffffu));
    a1 += bf2f((unsigned short)(v >> 16));
  }
  const int c0 = lane * 2;
  if (c0 < D)     out[(size_t)r * D + c0]     = a0;
  if (c0 + 1 < D) out[(size_t)r * D + c0 + 1] = a1;
}

extern "C" void kernel_launch(void* const* d_in, const int* in_sizes, int n_in,
                              void* d_out, int out_size, void* d_ws, size_t ws_size,
                              hipStream_t stream)
{
  (void)in_sizes; (void)n_in; (void)out_size; (void)ws_size;
  const float* atom_emb = (const float*)d_in[1];
  const int*   eidx     = (const int*)d_in[2];
  const int*   r2a      = (const int*)d_in[3];
  const float* lnW      = (const float*)d_in[4];
  const float* lnb      = (const float*)d_in[5];
  const float* Wl       = (const float*)d_in[6];
  const float* Wr       = (const float*)d_in[7];
  const float* bl       = (const float*)d_in[8];
  float* out = (float*)d_out;

  // workspace carve-out (~82 MB total)
  char* p = (char*)d_ws;
  auto alloc = [&](size_t b) { char* r = p; p += (b + 255) & ~(size_t)255; return r; };
  unsigned short* xb0  = (unsigned short*)alloc((size_t)MPAD * DP * 2);
  unsigned short* xb1  = (unsigned short*)alloc((size_t)MPAD * DP * 2);
  unsigned short* xb2  = (unsigned short*)alloc((size_t)MPAD * DP * 2);
  unsigned short* wpad = (unsigned short*)alloc((size_t)8 * 128 * 128 * 2);
  int*   hist      = (int*)alloc((size_t)N_ATOMS * 4);
  int*   row_start = (int*)alloc((size_t)(N_ATOMS + 1) * 4);
  int*   cursor    = (int*)alloc((size_t)N_ATOMS * 4);
  float* invdeg    = (float*)alloc((size_t)N_ATOMS * 4);
  int*   srcs      = (int*)alloc((size_t)N_EDGES * 4);
  int*   bsum      = (int*)alloc((size_t)256 * 4);
  int*   res_start = (int*)alloc((size_t)(N_RES + 1) * 4);

  hipMemsetAsync(hist, 0, (size_t)N_ATOMS * 4, stream);

  k_convw<<<dim3(128, 8), 128, 0, stream>>>(Wl, Wr, wpad);
  k_hist_edges<<<(N_EDGES + 255) / 256, 256, 0, stream>>>(eidx, hist);
  k_scan_part<<<NSCB, 256, 0, stream>>>(hist, bsum);
  k_scan_bsum<<<1, 256, 0, stream>>>(bsum, row_start + N_ATOMS);
  k_scan_final<<<NSCB, 256, 0, stream>>>(hist, bsum, row_start, cursor, invdeg);
  k_res_bounds<<<(N_RES + 1 + 255) / 256, 256, 0, stream>>>(r2a, res_start);
  k_fill<<<(N_EDGES + 255) / 256, 256, 0, stream>>>(eidx, cursor, srcs);
  k_proj<<<(N_ATOMS + 31) / 32, 128, 0, stream>>>(atom_emb, lnW, lnb, xb0);

  unsigned short* bufs[3] = {xb0, xb1, xb2};
  int cur = 0;
  for (int l = 0; l < N_LAYERS; ++l) {
    unsigned short* xin  = bufs[cur];
    unsigned short* aggb = bufs[(cur + 1) % 3];
    unsigned short* xo   = bufs[(cur + 2) % 3];
    k_agg<<<(N_ATOMS * 64) / 256, 256, 0, stream>>>(
        (const unsigned int*)xin, row_start, srcs, invdeg, (unsigned int*)aggb);
    k_gemm<<<MPAD / 128, 256, 0, stream>>>(
        aggb, xin, wpad + (size_t)l * 16384, wpad + (size_t)(4 + l) * 16384,
        bl + (size_t)l * D, xo);
    cur = (cur + 2) % 3;
  }
  k_pool<<<(N_RES * 64) / 256, 256, 0, stream>>>(
      (const unsigned int*)bufs[cur], res_start, out);
}

// Round 3
// 753.247 us; speedup vs baseline: 1.4702x; 1.1059x over previous
//
#include <hip/hip_runtime.h>
#include <hip/hip_bf16.h>

#define N_ATOMS 100000
#define N_RES   12500
#define N_EDGES 800000
#define D_IN    37
#define D       115
#define DP      128            // padded feature dim (bf16 row = 256 B)
#define MPAD    100096         // atoms padded to multiple of 128
#define N_LAYERS 4
#define SCE     1024           // elements per scan block (256 thr x 4)
#define NSCB    ((N_ATOMS + SCE - 1) / SCE)   // 98 scan blocks

typedef __bf16 bf16x8 __attribute__((ext_vector_type(8)));
typedef float  f32x4  __attribute__((ext_vector_type(4)));
typedef unsigned int u32x4 __attribute__((ext_vector_type(4)));

__device__ __forceinline__ unsigned short f2bf(float f) {
  unsigned u = __builtin_bit_cast(unsigned, f);
  u += 0x7fffu + ((u >> 16) & 1u);            // RNE
  return (unsigned short)(u >> 16);
}
__device__ __forceinline__ float bf2f(unsigned short h) {
  unsigned u = ((unsigned)h) << 16;
  return __builtin_bit_cast(float, u);
}
__device__ __forceinline__ bf16x8 ld_frag(const unsigned short* p) {
  u32x4 u = *reinterpret_cast<const u32x4*>(p);
  return __builtin_bit_cast(bf16x8, u);
}

// ---- CSR build -------------------------------------------------------------
__global__ void k_hist_edges(const int* __restrict__ eidx, int* __restrict__ hist) {
  int e = blockIdx.x * blockDim.x + threadIdx.x;
  if (e < N_EDGES) atomicAdd(&hist[eidx[N_EDGES + e]], 1);
}

// 3-phase device-wide exclusive scan over N_ATOMS counts
__global__ __launch_bounds__(256) void k_scan_part(
    const int* __restrict__ cnt, int* __restrict__ bsum)
{
  __shared__ int sh[256];
  const int t = threadIdx.x, b = blockIdx.x;
  const int base = b * SCE + t * 4;
  int s = 0;
  #pragma unroll
  for (int i = 0; i < 4; ++i) { int id = base + i; if (id < N_ATOMS) s += cnt[id]; }
  sh[t] = s; __syncthreads();
  for (int d = 128; d > 0; d >>= 1) { if (t < d) sh[t] += sh[t + d]; __syncthreads(); }
  if (t == 0) bsum[b] = sh[0];
}
__global__ __launch_bounds__(256) void k_scan_bsum(
    int* __restrict__ bsum, int* __restrict__ total)
{
  __shared__ int sh[256];
  const int t = threadIdx.x;
  int v = (t < NSCB) ? bsum[t] : 0;
  sh[t] = v; __syncthreads();
  for (int d = 1; d < 256; d <<= 1) {
    int u = (t >= d) ? sh[t - d] : 0;
    __syncthreads();
    sh[t] += u;
    __syncthreads();
  }
  if (t < NSCB) bsum[t] = sh[t] - v;          // exclusive
  if (t == 255) *total = sh[255];             // offs[N_ATOMS]
}
__global__ __launch_bounds__(256) void k_scan_final(
    const int* __restrict__ cnt, const int* __restrict__ bsum,
    int* __restrict__ offs, int* __restrict__ cursor, float* __restrict__ invdeg)
{
  __shared__ int sh[256];
  const int t = threadIdx.x, b = blockIdx.x;
  const int base = b * SCE + t * 4;
  int c[4]; int s = 0;
  #pragma unroll
  for (int i = 0; i < 4; ++i) {
    int id = base + i;
    c[i] = (id < N_ATOMS) ? cnt[id] : 0;
    s += c[i];
  }
  sh[t] = s; __syncthreads();
  for (int d = 1; d < 256; d <<= 1) {
    int u = (t >= d) ? sh[t - d] : 0;
    __syncthreads();
    sh[t] += u;
    __syncthreads();
  }
  int run = bsum[b] + sh[t] - s;              // exclusive prefix for this thread
  #pragma unroll
  for (int i = 0; i < 4; ++i) {
    int id = base + i;
    if (id < N_ATOMS) {
      offs[id] = run;
      cursor[id] = run;
      invdeg[id] = 1.0f / (float)max(c[i], 1);
      run += c[i];
    }
  }
}

// residue CSR via binary search (r2a is sorted): res_start[r] = lower_bound(r)
__global__ __launch_bounds__(256) void k_res_bounds(
    const int* __restrict__ r2a, int* __restrict__ res_start)
{
  int r = blockIdx.x * blockDim.x + threadIdx.x;
  if (r > N_RES) return;
  int lo = 0, hi = N_ATOMS;
  while (lo < hi) {
    int mid = (lo + hi) >> 1;
    if (r2a[mid] < r) lo = mid + 1; else hi = mid;
  }
  res_start[r] = lo;
}

__global__ void k_fill(const int* __restrict__ eidx, int* __restrict__ cursor,
                       int* __restrict__ srcs) {
  int e = blockIdx.x * blockDim.x + threadIdx.x;
  if (e < N_EDGES) {
    int s = eidx[e], d = eidx[N_EDGES + e];
    int pos = atomicAdd(&cursor[d], 1);
    srcs[pos] = s;
  }
}

// ---- weight pad/convert: W[115][115] f32 -> [128][128] bf16 (c-major) ------
__global__ void k_convw(const float* __restrict__ Wl, const float* __restrict__ Wr,
                        unsigned short* __restrict__ wpad)
{
  const int k = threadIdx.x;   // 0..127
  const int c = blockIdx.x;    // 0..127
  const int m = blockIdx.y;    // 0..7  (0-3 = Wl layers, 4-7 = Wr layers)
  const float* src = (m < 4) ? (Wl + m * D * D) : (Wr + (m - 4) * D * D);
  unsigned short v = 0;
  if (c < D && k < D) v = f2bf(src[c * D + k]);
  wpad[(m * 128 + c) * 128 + k] = v;
}

// ---- input projection: x0 = A @ lnW^T + lnb, write bf16 [MPAD][128] --------
__global__ __launch_bounds__(128) void k_proj(
    const float* __restrict__ A, const float* __restrict__ Wf,
    const float* __restrict__ bf, unsigned short* __restrict__ xout)
{
  __shared__ float sW[D * D_IN];
  __shared__ float sA[32][D_IN];
  const int t = threadIdx.x;
  for (int i = t; i < D * D_IN; i += 128) sW[i] = Wf[i];
  const int r0 = blockIdx.x * 32;
  for (int i = t; i < 32 * D_IN; i += 128) {
    int r = i / D_IN, k = i - r * D_IN;
    int gr = r0 + r;
    sA[r][k] = (gr < N_ATOMS) ? A[gr * D_IN + k] : 0.f;
  }
  __syncthreads();
  const int c = t;
  const float bias = (c < D) ? bf[c] : 0.f;
  for (int r = 0; r < 32; ++r) {
    const int gr = r0 + r;
    if (gr >= N_ATOMS) break;
    if (c < D) {
      float acc = bias;
      #pragma unroll
      for (int k = 0; k < D_IN; ++k) acc += sA[r][k] * sW[c * D_IN + k];
      xout[gr * DP + c] = f2bf(acc);
    } else {
      xout[gr * DP + c] = 0;   // keep K-pad zero
    }
  }
}

// ---- CSR mean aggregation: one wave per node, batched-ILP gather -----------
// Lanes 0-15 batch-load 16 src indices; __shfl broadcasts; 16 row-gathers
// issue independently (no per-edge pointer-chase).
__global__ __launch_bounds__(256) void k_agg(
    const unsigned int* __restrict__ xin, const int* __restrict__ row_start,
    const int* __restrict__ srcs, const float* __restrict__ invdeg,
    unsigned int* __restrict__ aggout)
{
  const int w = (int)((blockIdx.x * 256 + threadIdx.x) >> 6);
  const int lane = threadIdx.x & 63;
  if (w >= N_ATOMS) return;
  const int beg = row_start[w], end = row_start[w + 1];
  float a0 = 0.f, a1 = 0.f;
  for (int base = beg; base < end; base += 16) {
    const int m = end - base;                  // >=1
    int sidx = 0;
    if (lane < 16 && lane < m) sidx = srcs[base + lane];
    #pragma unroll
    for (int j = 0; j < 16; ++j) {
      const int s = __shfl(sidx, j);
      const unsigned int v = xin[(size_t)s * 64 + lane];  // independent loads
      if (j < m) {
        a0 += bf2f((unsigned short)(v & 0xffffu));
        a1 += bf2f((unsigned short)(v >> 16));
      }
    }
  }
  const float sc = invdeg[w];
  unsigned int o = (unsigned int)f2bf(a0 * sc) | ((unsigned int)f2bf(a1 * sc) << 16);
  aggout[w * 64 + lane] = o;
}

// ---- fused layer GEMM: xout = agg @ Wl^T + x @ Wr^T + bl  (K=256 concat) ---
__global__ __launch_bounds__(256) void k_gemm(
    const unsigned short* __restrict__ agg,
    const unsigned short* __restrict__ xin,
    const unsigned short* __restrict__ wl,   // [128][128] bf16, c-major
    const unsigned short* __restrict__ wr,
    const float* __restrict__ bias,          // 115 floats
    unsigned short* __restrict__ xout)
{
  const int lane = threadIdx.x & 63;
  const int wid  = threadIdx.x >> 6;
  const int row0 = blockIdx.x * 128 + wid * 32;   // wave owns 32 rows
  const int lrow = lane & 15;
  const int koff = (lane >> 4) * 8;

  f32x4 acc[2][8];
  #pragma unroll
  for (int i = 0; i < 2; ++i)
    #pragma unroll
    for (int j = 0; j < 8; ++j)
      acc[i][j] = (f32x4){0.f, 0.f, 0.f, 0.f};

  #pragma unroll
  for (int s = 0; s < 2; ++s) {
    const unsigned short* X = s ? xin : agg;
    const unsigned short* W = s ? wr : wl;
    #pragma unroll
    for (int ks = 0; ks < 4; ++ks) {
      const int k0 = ks * 32 + koff;
      bf16x8 a0 = ld_frag(&X[(size_t)(row0 + lrow) * DP + k0]);
      bf16x8 a1 = ld_frag(&X[(size_t)(row0 + 16 + lrow) * DP + k0]);
      #pragma unroll
      for (int ct = 0; ct < 8; ++ct) {
        bf16x8 b = ld_frag(&W[(ct * 16 + lrow) * DP + k0]);
        acc[0][ct] = __builtin_amdgcn_mfma_f32_16x16x32_bf16(a0, b, acc[0][ct], 0, 0, 0);
        acc[1][ct] = __builtin_amdgcn_mfma_f32_16x16x32_bf16(a1, b, acc[1][ct], 0, 0, 0);
      }
    }
  }

  const int ocol = lane & 15;
  const int orow = (lane >> 4) * 4;   // C/D: col=lane&15, row=(lane>>4)*4+reg
  #pragma unroll
  for (int ct = 0; ct < 8; ++ct) {
    const int col = ct * 16 + ocol;
    const float bv = (col < D) ? bias[col] : 0.f;
    #pragma unroll
    for (int rt = 0; rt < 2; ++rt) {
      #pragma unroll
      for (int j = 0; j < 4; ++j) {
        const int grow = row0 + rt * 16 + orow + j;
        if (grow < N_ATOMS)
          xout[(size_t)grow * DP + col] = f2bf(acc[rt][ct][j] + bv);
      }
    }
  }
}

// ---- residue pooling: sorted segment-sum, one wave per residue -------------
__global__ __launch_bounds__(256) void k_pool(
    const unsigned int* __restrict__ x, const int* __restrict__ res_start,
    float* __restrict__ out)
{
  const int r = (int)((blockIdx.x * 256 + threadIdx.x) >> 6);
  const int lane = threadIdx.x & 63;
  if (r >= N_RES) return;
  const int beg = res_start[r], end = res_start[r + 1];
  float a0 = 0.f, a1 = 0.f;
  for (int a = beg; a < end; ++a) {
    unsigned int v = x[a * 64 + lane];   // contiguous rows: already independent
    a0 += bf2f((unsigned short)(v & 0xffffu));
    a1 += bf2f((unsigned short)(v >> 16));
  }
  const int c0 = lane * 2;
  if (c0 < D)     out[(size_t)r * D + c0]     = a0;
  if (c0 + 1 < D) out[(size_t)r * D + c0 + 1] = a1;
}

extern "C" void kernel_launch(void* const* d_in, const int* in_sizes, int n_in,
                              void* d_out, int out_size, void* d_ws, size_t ws_size,
                              hipStream_t stream)
{
  (void)in_sizes; (void)n_in; (void)out_size; (void)ws_size;
  const float* atom_emb = (const float*)d_in[1];
  const int*   eidx     = (const int*)d_in[2];
  const int*   r2a      = (const int*)d_in[3];
  const float* lnW      = (const float*)d_in[4];
  const float* lnb      = (const float*)d_in[5];
  const float* Wl       = (const float*)d_in[6];
  const float* Wr       = (const float*)d_in[7];
  const float* bl       = (const float*)d_in[8];
  float* out = (float*)d_out;

  // workspace carve-out (~82 MB total)
  char* p = (char*)d_ws;
  auto alloc = [&](size_t b) { char* r = p; p += (b + 255) & ~(size_t)255; return r; };
  unsigned short* xb0  = (unsigned short*)alloc((size_t)MPAD * DP * 2);
  unsigned short* xb1  = (unsigned short*)alloc((size_t)MPAD * DP * 2);
  unsigned short* xb2  = (unsigned short*)alloc((size_t)MPAD * DP * 2);
  unsigned short* wpad = (unsigned short*)alloc((size_t)8 * 128 * 128 * 2);
  int*   hist      = (int*)alloc((size_t)N_ATOMS * 4);
  int*   row_start = (int*)alloc((size_t)(N_ATOMS + 1) * 4);
  int*   cursor    = (int*)alloc((size_t)N_ATOMS * 4);
  float* invdeg    = (float*)alloc((size_t)N_ATOMS * 4);
  int*   srcs      = (int*)alloc((size_t)N_EDGES * 4);
  int*   bsum      = (int*)alloc((size_t)256 * 4);
  int*   res_start = (int*)alloc((size_t)(N_RES + 1) * 4);

  hipMemsetAsync(hist, 0, (size_t)N_ATOMS * 4, stream);

  k_convw<<<dim3(128, 8), 128, 0, stream>>>(Wl, Wr, wpad);
  k_hist_edges<<<(N_EDGES + 255) / 256, 256, 0, stream>>>(eidx, hist);
  k_scan_part<<<NSCB, 256, 0, stream>>>(hist, bsum);
  k_scan_bsum<<<1, 256, 0, stream>>>(bsum, row_start + N_ATOMS);
  k_scan_final<<<NSCB, 256, 0, stream>>>(hist, bsum, row_start, cursor, invdeg);
  k_res_bounds<<<(N_RES + 1 + 255) / 256, 256, 0, stream>>>(r2a, res_start);
  k_fill<<<(N_EDGES + 255) / 256, 256, 0, stream>>>(eidx, cursor, srcs);
  k_proj<<<(N_ATOMS + 31) / 32, 128, 0, stream>>>(atom_emb, lnW, lnb, xb0);

  unsigned short* bufs[3] = {xb0, xb1, xb2};
  int cur = 0;
  for (int l = 0; l < N_LAYERS; ++l) {
    unsigned short* xin  = bufs[cur];
    unsigned short* aggb = bufs[(cur + 1) % 3];
    unsigned short* xo   = bufs[(cur + 2) % 3];
    k_agg<<<(N_ATOMS * 64) / 256, 256, 0, stream>>>(
        (const unsigned int*)xin, row_start, srcs, invdeg, (unsigned int*)aggb);
    k_gemm<<<MPAD / 128, 256, 0, stream>>>(
        aggb, xin, wpad + (size_t)l * 16384, wpad + (size_t)(4 + l) * 16384,
        bl + (size_t)l * D, xo);
    cur = (cur + 2) % 3;
  }
  k_pool<<<(N_RES * 64) / 256, 256, 0, stream>>>(
      (const unsigned int*)bufs[cur], res_start, out);
}

// Round 4
// 732.594 us; speedup vs baseline: 1.5117x; 1.0282x over previous
//
#include <hip/hip_runtime.h>
#include <hip/hip_bf16.h>

#define N_ATOMS 100000
#define N_RES   12500
#define N_EDGES 800000
#define D_IN    37
#define D       115
#define DP      128            // padded feature dim (bf16 row = 256 B)
#define MPAD    100096         // atoms padded to multiple of 128
#define N_LAYERS 4
#define SCE     1024           // elements per scan block (256 thr x 4)
#define NSCB    ((N_ATOMS + SCE - 1) / SCE)   // 98 scan blocks
#define KPROJ   64             // D_IN padded to MFMA K multiple
#define LSTRIDE 72             // LDS row stride in bf16 (144 B -> ~2-way banks, free)

typedef __bf16 bf16x8 __attribute__((ext_vector_type(8)));
typedef float  f32x4  __attribute__((ext_vector_type(4)));
typedef unsigned int u32x4 __attribute__((ext_vector_type(4)));

__device__ __forceinline__ unsigned short f2bf(float f) {
  unsigned u = __builtin_bit_cast(unsigned, f);
  u += 0x7fffu + ((u >> 16) & 1u);            // RNE
  return (unsigned short)(u >> 16);
}
__device__ __forceinline__ float bf2f(unsigned short h) {
  unsigned u = ((unsigned)h) << 16;
  return __builtin_bit_cast(float, u);
}
__device__ __forceinline__ bf16x8 ld_frag(const unsigned short* p) {
  u32x4 u = *reinterpret_cast<const u32x4*>(p);
  return __builtin_bit_cast(bf16x8, u);
}

// ---- CSR build -------------------------------------------------------------
__global__ void k_hist_edges(const int* __restrict__ eidx, int* __restrict__ hist) {
  int e = blockIdx.x * blockDim.x + threadIdx.x;
  if (e < N_EDGES) atomicAdd(&hist[eidx[N_EDGES + e]], 1);
}

// 3-phase device-wide exclusive scan over N_ATOMS counts
__global__ __launch_bounds__(256) void k_scan_part(
    const int* __restrict__ cnt, int* __restrict__ bsum)
{
  __shared__ int sh[256];
  const int t = threadIdx.x, b = blockIdx.x;
  const int base = b * SCE + t * 4;
  int s = 0;
  #pragma unroll
  for (int i = 0; i < 4; ++i) { int id = base + i; if (id < N_ATOMS) s += cnt[id]; }
  sh[t] = s; __syncthreads();
  for (int d = 128; d > 0; d >>= 1) { if (t < d) sh[t] += sh[t + d]; __syncthreads(); }
  if (t == 0) bsum[b] = sh[0];
}
__global__ __launch_bounds__(256) void k_scan_bsum(
    int* __restrict__ bsum, int* __restrict__ total)
{
  __shared__ int sh[256];
  const int t = threadIdx.x;
  int v = (t < NSCB) ? bsum[t] : 0;
  sh[t] = v; __syncthreads();
  for (int d = 1; d < 256; d <<= 1) {
    int u = (t >= d) ? sh[t - d] : 0;
    __syncthreads();
    sh[t] += u;
    __syncthreads();
  }
  if (t < NSCB) bsum[t] = sh[t] - v;          // exclusive
  if (t == 255) *total = sh[255];             // offs[N_ATOMS]
}
__global__ __launch_bounds__(256) void k_scan_final(
    const int* __restrict__ cnt, const int* __restrict__ bsum,
    int* __restrict__ offs, int* __restrict__ cursor, float* __restrict__ invdeg)
{
  __shared__ int sh[256];
  const int t = threadIdx.x, b = blockIdx.x;
  const int base = b * SCE + t * 4;
  int c[4]; int s = 0;
  #pragma unroll
  for (int i = 0; i < 4; ++i) {
    int id = base + i;
    c[i] = (id < N_ATOMS) ? cnt[id] : 0;
    s += c[i];
  }
  sh[t] = s; __syncthreads();
  for (int d = 1; d < 256; d <<= 1) {
    int u = (t >= d) ? sh[t - d] : 0;
    __syncthreads();
    sh[t] += u;
    __syncthreads();
  }
  int run = bsum[b] + sh[t] - s;              // exclusive prefix for this thread
  #pragma unroll
  for (int i = 0; i < 4; ++i) {
    int id = base + i;
    if (id < N_ATOMS) {
      offs[id] = run;
      cursor[id] = run;
      invdeg[id] = 1.0f / (float)max(c[i], 1);
      run += c[i];
    }
  }
}

// residue CSR via binary search (r2a is sorted): res_start[r] = lower_bound(r)
__global__ __launch_bounds__(256) void k_res_bounds(
    const int* __restrict__ r2a, int* __restrict__ res_start)
{
  int r = blockIdx.x * blockDim.x + threadIdx.x;
  if (r > N_RES) return;
  int lo = 0, hi = N_ATOMS;
  while (lo < hi) {
    int mid = (lo + hi) >> 1;
    if (r2a[mid] < r) lo = mid + 1; else hi = mid;
  }
  res_start[r] = lo;
}

__global__ void k_fill(const int* __restrict__ eidx, int* __restrict__ cursor,
                       int* __restrict__ srcs) {
  int e = blockIdx.x * blockDim.x + threadIdx.x;
  if (e < N_EDGES) {
    int s = eidx[e], d = eidx[N_EDGES + e];
    int pos = atomicAdd(&cursor[d], 1);
    srcs[pos] = s;
  }
}

// ---- weight pad/convert: W[115][115] f32 -> [128][128] bf16 (c-major) ------
__global__ void k_convw(const float* __restrict__ Wl, const float* __restrict__ Wr,
                        unsigned short* __restrict__ wpad)
{
  const int k = threadIdx.x;   // 0..127
  const int c = blockIdx.x;    // 0..127
  const int m = blockIdx.y;    // 0..7  (0-3 = Wl layers, 4-7 = Wr layers)
  const float* src = (m < 4) ? (Wl + m * D * D) : (Wr + (m - 4) * D * D);
  unsigned short v = 0;
  if (c < D && k < D) v = f2bf(src[c * D + k]);
  wpad[(m * 128 + c) * 128 + k] = v;
}

// ---- input projection via MFMA: x0 = A @ lnW^T + lnb, bf16 [MPAD][128] -----
// 128 rows/block, 4 waves x 32 rows. A-tile & W staged in LDS as bf16,
// K padded 37->64, LDS row stride 72 bf16 (144 B) for conflict-free b128 reads.
__global__ __launch_bounds__(256) void k_proj(
    const float* __restrict__ A, const float* __restrict__ Wf,
    const float* __restrict__ bf, unsigned short* __restrict__ xout)
{
  __shared__ unsigned short sA[128 * LSTRIDE];
  __shared__ unsigned short sW[128 * LSTRIDE];
  const int t = threadIdx.x;
  const int r0 = blockIdx.x * 128;

  // stage A: [128][64] bf16 (zero pad k>=37, rows >= N_ATOMS)
  for (int idx = t; idx < 128 * KPROJ; idx += 256) {
    const int row = idx >> 6, k = idx & 63;
    const int gr = r0 + row;
    unsigned short v = 0;
    if (k < D_IN && gr < N_ATOMS) v = f2bf(A[(size_t)gr * D_IN + k]);
    sA[row * LSTRIDE + k] = v;
  }
  // stage W: [128 cols][64] bf16 (zero pad col>=115, k>=37)
  for (int idx = t; idx < 128 * KPROJ; idx += 256) {
    const int col = idx >> 6, k = idx & 63;
    unsigned short v = 0;
    if (col < D && k < D_IN) v = f2bf(Wf[col * D_IN + k]);
    sW[col * LSTRIDE + k] = v;
  }
  __syncthreads();

  const int lane = t & 63;
  const int wid  = t >> 6;
  const int wrow = wid * 32;           // wave's 32 rows within block
  const int lrow = lane & 15;
  const int koff = (lane >> 4) * 8;

  f32x4 acc[2][8];
  #pragma unroll
  for (int i = 0; i < 2; ++i)
    #pragma unroll
    for (int j = 0; j < 8; ++j)
      acc[i][j] = (f32x4){0.f, 0.f, 0.f, 0.f};

  #pragma unroll
  for (int ks = 0; ks < 2; ++ks) {     // K = 64 -> two 16x16x32 steps
    const int k0 = ks * 32 + koff;
    bf16x8 a0 = ld_frag(&sA[(wrow + lrow) * LSTRIDE + k0]);
    bf16x8 a1 = ld_frag(&sA[(wrow + 16 + lrow) * LSTRIDE + k0]);
    #pragma unroll
    for (int ct = 0; ct < 8; ++ct) {
      bf16x8 b = ld_frag(&sW[(ct * 16 + lrow) * LSTRIDE + k0]);
      acc[0][ct] = __builtin_amdgcn_mfma_f32_16x16x32_bf16(a0, b, acc[0][ct], 0, 0, 0);
      acc[1][ct] = __builtin_amdgcn_mfma_f32_16x16x32_bf16(a1, b, acc[1][ct], 0, 0, 0);
    }
  }

  const int ocol = lane & 15;
  const int orow = (lane >> 4) * 4;    // C/D: col=lane&15, row=(lane>>4)*4+reg
  #pragma unroll
  for (int ct = 0; ct < 8; ++ct) {
    const int col = ct * 16 + ocol;
    const float bv = (col < D) ? bf[col] : 0.f;   // pad cols: acc=0, bv=0 -> stays 0
    #pragma unroll
    for (int rt = 0; rt < 2; ++rt) {
      #pragma unroll
      for (int j = 0; j < 4; ++j) {
        const int grow = r0 + wrow + rt * 16 + orow + j;
        if (grow < N_ATOMS)
          xout[(size_t)grow * DP + col] = f2bf(acc[rt][ct][j] + bv);
      }
    }
  }
}

// ---- CSR mean aggregation: one wave per node, batched-ILP gather -----------
__global__ __launch_bounds__(256) void k_agg(
    const unsigned int* __restrict__ xin, const int* __restrict__ row_start,
    const int* __restrict__ srcs, const float* __restrict__ invdeg,
    unsigned int* __restrict__ aggout)
{
  const int w = (int)((blockIdx.x * 256 + threadIdx.x) >> 6);
  const int lane = threadIdx.x & 63;
  if (w >= N_ATOMS) return;
  const int beg = row_start[w], end = row_start[w + 1];
  float a0 = 0.f, a1 = 0.f;
  for (int base = beg; base < end; base += 16) {
    const int m = end - base;                  // >=1
    int sidx = 0;
    if (lane < 16 && lane < m) sidx = srcs[base + lane];
    #pragma unroll
    for (int j = 0; j < 16; ++j) {
      const int s = __shfl(sidx, j);
      const unsigned int v = xin[(size_t)s * 64 + lane];  // independent loads
      if (j < m) {
        a0 += bf2f((unsigned short)(v & 0xffffu));
        a1 += bf2f((unsigned short)(v >> 16));
      }
    }
  }
  const float sc = invdeg[w];
  unsigned int o = (unsigned int)f2bf(a0 * sc) | ((unsigned int)f2bf(a1 * sc) << 16);
  aggout[w * 64 + lane] = o;
}

// ---- fused layer GEMM: xout = agg @ Wl^T + x @ Wr^T + bl  (K=256 concat) ---
__global__ __launch_bounds__(256) void k_gemm(
    const unsigned short* __restrict__ agg,
    const unsigned short* __restrict__ xin,
    const unsigned short* __restrict__ wl,   // [128][128] bf16, c-major
    const unsigned short* __restrict__ wr,
    const float* __restrict__ bias,          // 115 floats
    unsigned short* __restrict__ xout)
{
  const int lane = threadIdx.x & 63;
  const int wid  = threadIdx.x >> 6;
  const int row0 = blockIdx.x * 128 + wid * 32;   // wave owns 32 rows
  const int lrow = lane & 15;
  const int koff = (lane >> 4) * 8;

  f32x4 acc[2][8];
  #pragma unroll
  for (int i = 0; i < 2; ++i)
    #pragma unroll
    for (int j = 0; j < 8; ++j)
      acc[i][j] = (f32x4){0.f, 0.f, 0.f, 0.f};

  #pragma unroll
  for (int s = 0; s < 2; ++s) {
    const unsigned short* X = s ? xin : agg;
    const unsigned short* W = s ? wr : wl;
    #pragma unroll
    for (int ks = 0; ks < 4; ++ks) {
      const int k0 = ks * 32 + koff;
      bf16x8 a0 = ld_frag(&X[(size_t)(row0 + lrow) * DP + k0]);
      bf16x8 a1 = ld_frag(&X[(size_t)(row0 + 16 + lrow) * DP + k0]);
      #pragma unroll
      for (int ct = 0; ct < 8; ++ct) {
        bf16x8 b = ld_frag(&W[(ct * 16 + lrow) * DP + k0]);
        acc[0][ct] = __builtin_amdgcn_mfma_f32_16x16x32_bf16(a0, b, acc[0][ct], 0, 0, 0);
        acc[1][ct] = __builtin_amdgcn_mfma_f32_16x16x32_bf16(a1, b, acc[1][ct], 0, 0, 0);
      }
    }
  }

  const int ocol = lane & 15;
  const int orow = (lane >> 4) * 4;   // C/D: col=lane&15, row=(lane>>4)*4+reg
  #pragma unroll
  for (int ct = 0; ct < 8; ++ct) {
    const int col = ct * 16 + ocol;
    const float bv = (col < D) ? bias[col] : 0.f;
    #pragma unroll
    for (int rt = 0; rt < 2; ++rt) {
      #pragma unroll
      for (int j = 0; j < 4; ++j) {
        const int grow = row0 + rt * 16 + orow + j;
        if (grow < N_ATOMS)
          xout[(size_t)grow * DP + col] = f2bf(acc[rt][ct][j] + bv);
      }
    }
  }
}

// ---- residue pooling: sorted segment-sum, one wave per residue -------------
__global__ __launch_bounds__(256) void k_pool(
    const unsigned int* __restrict__ x, const int* __restrict__ res_start,
    float* __restrict__ out)
{
  const int r = (int)((blockIdx.x * 256 + threadIdx.x) >> 6);
  const int lane = threadIdx.x & 63;
  if (r >= N_RES) return;
  const int beg = res_start[r], end = res_start[r + 1];
  float a0 = 0.f, a1 = 0.f;
  for (int a = beg; a < end; ++a) {
    unsigned int v = x[a * 64 + lane];   // contiguous rows: already independent
    a0 += bf2f((unsigned short)(v & 0xffffu));
    a1 += bf2f((unsigned short)(v >> 16));
  }
  const int c0 = lane * 2;
  if (c0 < D)     out[(size_t)r * D + c0]     = a0;
  if (c0 + 1 < D) out[(size_t)r * D + c0 + 1] = a1;
}

extern "C" void kernel_launch(void* const* d_in, const int* in_sizes, int n_in,
                              void* d_out, int out_size, void* d_ws, size_t ws_size,
                              hipStream_t stream)
{
  (void)in_sizes; (void)n_in; (void)out_size; (void)ws_size;
  const float* atom_emb = (const float*)d_in[1];
  const int*   eidx     = (const int*)d_in[2];
  const int*   r2a      = (const int*)d_in[3];
  const float* lnW      = (const float*)d_in[4];
  const float* lnb      = (const float*)d_in[5];
  const float* Wl       = (const float*)d_in[6];
  const float* Wr       = (const float*)d_in[7];
  const float* bl       = (const float*)d_in[8];
  float* out = (float*)d_out;

  // workspace carve-out (~82 MB total)
  char* p = (char*)d_ws;
  auto alloc = [&](size_t b) { char* r = p; p += (b + 255) & ~(size_t)255; return r; };
  unsigned short* xb0  = (unsigned short*)alloc((size_t)MPAD * DP * 2);
  unsigned short* xb1  = (unsigned short*)alloc((size_t)MPAD * DP * 2);
  unsigned short* xb2  = (unsigned short*)alloc((size_t)MPAD * DP * 2);
  unsigned short* wpad = (unsigned short*)alloc((size_t)8 * 128 * 128 * 2);
  int*   hist      = (int*)alloc((size_t)N_ATOMS * 4);
  int*   row_start = (int*)alloc((size_t)(N_ATOMS + 1) * 4);
  int*   cursor    = (int*)alloc((size_t)N_ATOMS * 4);
  float* invdeg    = (float*)alloc((size_t)N_ATOMS * 4);
  int*   srcs      = (int*)alloc((size_t)N_EDGES * 4);
  int*   bsum      = (int*)alloc((size_t)256 * 4);
  int*   res_start = (int*)alloc((size_t)(N_RES + 1) * 4);

  hipMemsetAsync(hist, 0, (size_t)N_ATOMS * 4, stream);

  k_convw<<<dim3(128, 8), 128, 0, stream>>>(Wl, Wr, wpad);
  k_hist_edges<<<(N_EDGES + 255) / 256, 256, 0, stream>>>(eidx, hist);
  k_scan_part<<<NSCB, 256, 0, stream>>>(hist, bsum);
  k_scan_bsum<<<1, 256, 0, stream>>>(bsum, row_start + N_ATOMS);
  k_scan_final<<<NSCB, 256, 0, stream>>>(hist, bsum, row_start, cursor, invdeg);
  k_res_bounds<<<(N_RES + 1 + 255) / 256, 256, 0, stream>>>(r2a, res_start);
  k_fill<<<(N_EDGES + 255) / 256, 256, 0, stream>>>(eidx, cursor, srcs);
  k_proj<<<MPAD / 128, 256, 0, stream>>>(atom_emb, lnW, lnb, xb0);

  unsigned short* bufs[3] = {xb0, xb1, xb2};
  int cur = 0;
  for (int l = 0; l < N_LAYERS; ++l) {
    unsigned short* xin  = bufs[cur];
    unsigned short* aggb = bufs[(cur + 1) % 3];
    unsigned short* xo   = bufs[(cur + 2) % 3];
    k_agg<<<(N_ATOMS * 64) / 256, 256, 0, stream>>>(
        (const unsigned int*)xin, row_start, srcs, invdeg, (unsigned int*)aggb);
    k_gemm<<<MPAD / 128, 256, 0, stream>>>(
        aggb, xin, wpad + (size_t)l * 16384, wpad + (size_t)(4 + l) * 16384,
        bl + (size_t)l * D, xo);
    cur = (cur + 2) % 3;
  }
  k_pool<<<(N_RES * 64) / 256, 256, 0, stream>>>(
      (const unsigned int*)bufs[cur], res_start, out);
}